// Round 2
// baseline (686.621 us; speedup 1.0000x reference)
//
#include <hip/hip_runtime.h>

#define DD 256        // d_model
#define SD 260        // padded LDS row stride (words)
#define AA 64         // attn dim
#define KK 16         // neighbors
#define MM 16         // rows per block
#define KT 16         // k-tile for weight staging
#define WS 17         // s_w row stride (words), odd => good ds_read_b128 pattern

extern "C" __global__ __launch_bounds__(256)
void na_f32_kernel(const float* __restrict__ embs,
                   const int* __restrict__ center_idx,
                   const int* __restrict__ nb_idx,
                   const float* __restrict__ nb_w,
                   const float* __restrict__ Wq,
                   const float* __restrict__ Wk,
                   const float* __restrict__ Wg,
                   const float* __restrict__ bg,
                   const float* __restrict__ Wo,
                   const float* __restrict__ bo,
                   const float* __restrict__ gamma,
                   const float* __restrict__ beta,
                   float* __restrict__ out)
{
    __shared__ __align__(16) float s_center[MM][SD];  // 16.6 KB
    __shared__ __align__(16) float s_tc[MM][SD];      // 16.6 KB: t_all -> ctx -> x
    __shared__ __align__(16) float s_nb[KK][SD];      // 16.6 KB
    __shared__ __align__(16) float s_w[DD][WS];       // 17.4 KB weight staging
    __shared__ __align__(16) float s_q[MM][AA];       // 4 KB
    __shared__ float s_red[KK][16];
    __shared__ float s_attn[KK];

    const int tid = threadIdx.x;
    const int row0 = blockIdx.x * MM;
    const int td = tid & 63;   // col tile: cols 4*td .. 4*td+3
    const int tm = tid >> 6;   // row tile: rows 4*tm .. 4*tm+3

    // ---- P1: gather 16 center rows -> LDS ----
    {
        int m = tid >> 4, c = tid & 15;
        int idx = center_idx[row0 + m];
        const float4* src = (const float4*)(embs + (size_t)idx * DD) + c * 4;
        float4* dst = (float4*)&s_center[m][c * 16];
        dst[0] = src[0]; dst[1] = src[1]; dst[2] = src[2]; dst[3] = src[3];
    }
    __syncthreads();

    // ---- P2: q[m][a] = center[m] . Wq[a]  (staged GEMM, out-cols = 64) ----
    {
        const int a = tid & 63, mg = tid >> 6;
        float qacc[4] = {0.f, 0.f, 0.f, 0.f};
        for (int kt = 0; kt < DD; kt += KT) {
            __syncthreads();   // protect s_w reuse
            {   // stage Wq[0..63][kt..kt+KT): 64 rows x 4 float4, one per thread
                int r = tid >> 2, c4 = (tid & 3) * 4;
                *(float4*)&s_w[r][c4] = *(const float4*)(Wq + r * DD + kt + c4);
            }
            __syncthreads();
            #pragma unroll
            for (int kk = 0; kk < KT; kk += 4) {
                float4 b = *(const float4*)&s_w[a][kk];
                #pragma unroll
                for (int i = 0; i < 4; ++i) {
                    float4 av = *(const float4*)&s_center[4 * mg + i][kt + kk];
                    qacc[i] += av.x * b.x + av.y * b.y + av.z * b.z + av.w * b.w;
                }
            }
        }
        __syncthreads();
        #pragma unroll
        for (int i = 0; i < 4; ++i) s_q[4 * mg + i][a] = qacc[i];
    }
    __syncthreads();

    // ---- P2b: t_all[m][d] = sum_a q[m][a] * Wk[a][d]  (Wk is k-major: direct global B-frags) ----
    {
        float tacc[4][4];
        #pragma unroll
        for (int i = 0; i < 4; ++i)
            #pragma unroll
            for (int j = 0; j < 4; ++j) tacc[i][j] = 0.f;
        for (int kk = 0; kk < AA; kk += 4) {
            float4 bk[4];
            #pragma unroll
            for (int t4 = 0; t4 < 4; ++t4)
                bk[t4] = *(const float4*)(Wk + (size_t)(kk + t4) * DD + 4 * td);  // cols 4td..+3
            #pragma unroll
            for (int i = 0; i < 4; ++i) {
                float4 av = *(const float4*)&s_q[4 * tm + i][kk];  // broadcast
                tacc[i][0] += av.x * bk[0].x + av.y * bk[1].x + av.z * bk[2].x + av.w * bk[3].x;
                tacc[i][1] += av.x * bk[0].y + av.y * bk[1].y + av.z * bk[2].y + av.w * bk[3].y;
                tacc[i][2] += av.x * bk[0].z + av.y * bk[1].z + av.z * bk[2].z + av.w * bk[3].z;
                tacc[i][3] += av.x * bk[0].w + av.y * bk[1].w + av.z * bk[2].w + av.w * bk[3].w;
            }
        }
        #pragma unroll
        for (int i = 0; i < 4; ++i)
            *(float4*)&s_tc[4 * tm + i][4 * td] =
                make_float4(tacc[i][0], tacc[i][1], tacc[i][2], tacc[i][3]);
    }
    __syncthreads();

    // ---- P3: attention per row; ctx overwrites s_tc[m] ----
    for (int m = 0; m < MM; ++m) {
        {   // stage 16 neighbor rows
            int k = tid >> 4, c = tid & 15;
            int idx = nb_idx[(row0 + m) * KK + k];
            const float4* src = (const float4*)(embs + (size_t)idx * DD) + c * 4;
            float4* dst = (float4*)&s_nb[k][c * 16];
            dst[0] = src[0]; dst[1] = src[1]; dst[2] = src[2]; dst[3] = src[3];
        }
        __syncthreads();
        {   // logits partials: 16 threads per k, 16 elems each (float4)
            int k = tid >> 4, i = tid & 15;
            float acc = 0.f;
            #pragma unroll
            for (int j4 = 0; j4 < 4; ++j4) {
                float4 nv = *(const float4*)&s_nb[k][i * 16 + 4 * j4];
                float4 tv = *(const float4*)&s_tc[m][i * 16 + 4 * j4];
                acc += nv.x * tv.x + nv.y * tv.y + nv.z * tv.z + nv.w * tv.w;
            }
            s_red[k][i] = acc;
        }
        __syncthreads();
        if (tid < KK) {
            float lg = 0.f;
            #pragma unroll
            for (int i = 0; i < 16; ++i) lg += s_red[tid][i];
            float wv = nb_w[(row0 + m) * KK + tid];
            lg = lg * 0.125f + logf(fmaxf(wv, 1e-6f));
            float mx = lg;
            #pragma unroll
            for (int off = 8; off >= 1; off >>= 1) mx = fmaxf(mx, __shfl_xor(mx, off));
            float e = expf(lg - mx);
            float s = e;
            #pragma unroll
            for (int off = 8; off >= 1; off >>= 1) s += __shfl_xor(s, off);
            s_attn[tid] = e / s;
        }
        __syncthreads();
        {   // ctx[m][d] = sum_k attn[k]*nb[k][d]  -> overwrite s_tc[m]
            float acc = 0.f;
            #pragma unroll
            for (int k = 0; k < KK; ++k) acc += s_attn[k] * s_nb[k][tid];
            s_tc[m][tid] = acc;
        }
        __syncthreads();
    }

    // ---- P4: gate GEMM: acc[m][c] = center[m] . Wg[c]; s_tc *= sigmoid(acc+bg) ----
    {
        float acc[4][4];
        #pragma unroll
        for (int i = 0; i < 4; ++i)
            #pragma unroll
            for (int j = 0; j < 4; ++j) acc[i][j] = 0.f;
        for (int kt = 0; kt < DD; kt += KT) {
            __syncthreads();
            #pragma unroll
            for (int j = 0; j < 4; ++j) {   // stage Wg[0..255][kt..kt+KT)
                int r = (tid >> 2) + 64 * j;
                int c4 = (tid & 3) * 4;
                *(float4*)&s_w[r][c4] = *(const float4*)(Wg + (size_t)r * DD + kt + c4);
            }
            __syncthreads();
            #pragma unroll
            for (int kk = 0; kk < KT; kk += 4) {
                float4 b[4];
                #pragma unroll
                for (int j = 0; j < 4; ++j) b[j] = *(const float4*)&s_w[4 * td + j][kk];
                #pragma unroll
                for (int i = 0; i < 4; ++i) {
                    float4 av = *(const float4*)&s_center[4 * tm + i][kt + kk];
                    #pragma unroll
                    for (int j = 0; j < 4; ++j)
                        acc[i][j] += av.x * b[j].x + av.y * b[j].y + av.z * b[j].z + av.w * b[j].w;
                }
            }
        }
        float bgv[4];
        #pragma unroll
        for (int j = 0; j < 4; ++j) bgv[j] = bg[4 * td + j];
        __syncthreads();   // all FMA reads of s_w/s_tc done; safe to modify s_tc
        #pragma unroll
        for (int i = 0; i < 4; ++i)
            #pragma unroll
            for (int j = 0; j < 4; ++j) {
                float g = 1.f / (1.f + expf(-(acc[i][j] + bgv[j])));
                s_tc[4 * tm + i][4 * td + j] *= g;
            }
    }

    // ---- P5: out GEMM over k=512: A = [center | gated ctx], B = Wo ----
    {
        float acc[4][4];
        #pragma unroll
        for (int i = 0; i < 4; ++i)
            #pragma unroll
            for (int j = 0; j < 4; ++j) acc[i][j] = 0.f;
        for (int kt = 0; kt < 2 * DD; kt += KT) {
            __syncthreads();
            #pragma unroll
            for (int j = 0; j < 4; ++j) {   // stage Wo[0..255][kt..kt+KT)
                int r = (tid >> 2) + 64 * j;
                int c4 = (tid & 3) * 4;
                *(float4*)&s_w[r][c4] = *(const float4*)(Wo + (size_t)r * 2 * DD + kt + c4);
            }
            __syncthreads();
            const float* Abase = (kt < DD) ? &s_center[0][0] : &s_tc[0][0];
            const int kb = (kt < DD) ? kt : kt - DD;
            #pragma unroll
            for (int kk = 0; kk < KT; kk += 4) {
                float4 b[4];
                #pragma unroll
                for (int j = 0; j < 4; ++j) b[j] = *(const float4*)&s_w[4 * td + j][kk];
                #pragma unroll
                for (int i = 0; i < 4; ++i) {
                    float4 av = *(const float4*)(Abase + (4 * tm + i) * SD + kb + kk);
                    #pragma unroll
                    for (int j = 0; j < 4; ++j)
                        acc[i][j] += av.x * b[j].x + av.y * b[j].y + av.z * b[j].z + av.w * b[j].w;
                }
            }
        }
        float bov[4];
        #pragma unroll
        for (int j = 0; j < 4; ++j) bov[j] = bo[4 * td + j];
        __syncthreads();   // all A-reads of s_tc complete before overwrite with x
        #pragma unroll
        for (int i = 0; i < 4; ++i)
            #pragma unroll
            for (int j = 0; j < 4; ++j)
                s_tc[4 * tm + i][4 * td + j] =
                    acc[i][j] + bov[j] + s_center[4 * tm + i][4 * td + j];
    }
    __syncthreads();

    // ---- P6: LayerNorm per row, f32 out ----
    {
        int wv = tid >> 6, lane = tid & 63;
        #pragma unroll
        for (int jj = 0; jj < 4; ++jj) {
            int m = wv * 4 + jj;
            float x0 = s_tc[m][lane],       x1 = s_tc[m][64 + lane];
            float x2 = s_tc[m][128 + lane], x3 = s_tc[m][192 + lane];
            float s  = x0 + x1 + x2 + x3;
            float ss = x0 * x0 + x1 * x1 + x2 * x2 + x3 * x3;
            #pragma unroll
            for (int off = 32; off >= 1; off >>= 1) {
                s  += __shfl_xor(s, off);
                ss += __shfl_xor(ss, off);
            }
            float mu  = s * (1.f / 256.f);
            float var = ss * (1.f / 256.f) - mu * mu;
            float rs  = rsqrtf(var + 1e-5f);
            size_t base = (size_t)(row0 + m) * DD;
            float xs[4] = {x0, x1, x2, x3};
            #pragma unroll
            for (int c = 0; c < 4; ++c) {
                int dd = c * 64 + lane;
                out[base + dd] = (xs[c] - mu) * rs * gamma[dd] + beta[dd];
            }
        }
    }
}

extern "C" void kernel_launch(void* const* d_in, const int* in_sizes, int n_in,
                              void* d_out, int out_size, void* d_ws, size_t ws_size,
                              hipStream_t stream) {
    const float* embs  = (const float*)d_in[0];
    const int*   cidx  = (const int*)d_in[1];
    const int*   nidx  = (const int*)d_in[2];
    const float* nbw   = (const float*)d_in[3];
    const float* Wq    = (const float*)d_in[4];
    const float* Wk    = (const float*)d_in[5];
    const float* Wg    = (const float*)d_in[6];
    const float* bg    = (const float*)d_in[7];
    const float* Wo    = (const float*)d_in[8];
    const float* bo    = (const float*)d_in[9];
    const float* gamma = (const float*)d_in[10];
    const float* beta  = (const float*)d_in[11];
    float* out = (float*)d_out;

    const int B = in_sizes[1];   // 32768
    dim3 grid(B / MM), block(256);
    hipLaunchKernelGGL(na_f32_kernel, grid, block, 0, stream,
                       embs, cidx, nidx, nbw, Wq, Wk, Wg, bg, Wo, bo, gamma, beta, out);
}

// Round 3
// 268.891 us; speedup vs baseline: 2.5535x; 2.5535x over previous
//
#include <hip/hip_runtime.h>

#define DD 256
#define KK 16
#define MM 16

typedef __attribute__((ext_vector_type(8))) short bfrag;   // 8 bf16 (4 VGPRs)
typedef __attribute__((ext_vector_type(4))) float ffrag;   // 4 f32 acc

__device__ __forceinline__ float lo2f(unsigned int p){ union{unsigned int i; float f;} v; v.i = p<<16; return v.f; }
__device__ __forceinline__ float hi2f(unsigned int p){ union{unsigned int i; float f;} v; v.i = p & 0xffff0000u; return v.f; }
__device__ __forceinline__ float bf2f(unsigned short u){ union{unsigned int i; float f;} v; v.i = ((unsigned int)u)<<16; return v.f; }
__device__ __forceinline__ unsigned short f2b(float x){            // RNE bf16
    union{float f; unsigned int i;} v; v.f = x;
    unsigned int r = v.i + 0x7fffu + ((v.i>>16)&1u);
    return (unsigned short)(r>>16);
}
__device__ __forceinline__ unsigned int pack2(float a, float b){
    return (unsigned int)f2b(a) | ((unsigned int)f2b(b)<<16);
}

// ---------------- prepass: Mt = Wq^T*Wk (bf16), Wg/Wo -> bf16 ----------------
// ws layout (bf16 elems): [0,65536) Mt[d][e]; [65536,131072) Wg[r][k]; [131072,262144) Wo[r][k]
extern "C" __global__ __launch_bounds__(256)
void prep_weights(const float* __restrict__ Wq, const float* __restrict__ Wk,
                  const float* __restrict__ Wg, const float* __restrict__ Wo,
                  unsigned short* __restrict__ ws)
{
    int bid = blockIdx.x, e = threadIdx.x;
    if (bid < 256) {
        int d = bid; float acc = 0.f;
        #pragma unroll 8
        for (int a = 0; a < 64; ++a) acc = fmaf(Wq[a*256 + e], Wk[a*256 + d], acc);
        ws[d*256 + e] = f2b(acc);
    } else if (bid < 512) {
        int r = bid - 256;
        ws[65536 + r*256 + e] = f2b(Wg[r*256 + e]);
    } else {
        int r = bid - 512;
        ws[131072 + r*512 + e]       = f2b(Wo[r*512 + e]);
        ws[131072 + r*512 + 256 + e] = f2b(Wo[r*512 + 256 + e]);
    }
}

extern "C" __global__ __launch_bounds__(256)
void cvt_table(const float* __restrict__ src, unsigned short* __restrict__ dst, int n8)
{
    int i = blockIdx.x*256 + threadIdx.x;
    if (i < n8) {
        const float4* s = (const float4*)src + (size_t)i*2;
        float4 a = s[0], b = s[1];
        uint4 o;
        o.x = pack2(a.x,a.y); o.y = pack2(a.z,a.w);
        o.z = pack2(b.x,b.y); o.w = pack2(b.z,b.w);
        ((uint4*)dst)[i] = o;
    }
}

// ---------------- main fused kernel (MFMA) ----------------
template<bool TBF>
__global__ __launch_bounds__(256, 3)
void na_mfma_kernel(const float* __restrict__ embs,
                    const int* __restrict__ cidx,
                    const int* __restrict__ nidx,
                    const float* __restrict__ nbw,
                    const unsigned short* __restrict__ tbl,   // bf16 table (TBF)
                    const unsigned short* __restrict__ wMt,
                    const unsigned short* __restrict__ wWg,
                    const unsigned short* __restrict__ wWo,
                    const float* __restrict__ bg,
                    const float* __restrict__ bo,
                    const float* __restrict__ gamma,
                    const float* __restrict__ beta,
                    float* __restrict__ out)
{
    __shared__ __align__(16) unsigned short s_ac[16][264];  // center bf16 (A-frags)
    __shared__ __align__(16) unsigned short s_ax[16][264];  // ctx bf16 (A-frags)
    __shared__ __align__(16) unsigned short s_nb[32][264];  // 2 rows x 16 neighbors bf16
    __shared__ __align__(16) float s_t[16][260];            // t (f32) -> later x (f32)
    __shared__ float s_red[32][8];
    __shared__ float s_attn[32];
    __shared__ int   s_cidx[16];

    const int tid  = threadIdx.x;
    const int row0 = blockIdx.x * MM;
    const int lane = tid & 63, wv = tid >> 6;
    const int l15  = lane & 15, quad = lane >> 4;
    const ffrag fz = {0.f, 0.f, 0.f, 0.f};

    // ---- P1: stage 16 center rows (f32 -> bf16) ----
    {
        if (tid < 16) s_cidx[tid] = cidx[row0 + tid];
        int m = tid >> 4, cs = tid & 15;
        int idx = cidx[row0 + m];
        const float4* src = (const float4*)(embs + (size_t)idx * DD + cs * 16);
        float4 a = src[0], b = src[1], c2 = src[2], d2 = src[3];
        uint4 o0, o1;
        o0.x = pack2(a.x,a.y);  o0.y = pack2(a.z,a.w);
        o0.z = pack2(b.x,b.y);  o0.w = pack2(b.z,b.w);
        o1.x = pack2(c2.x,c2.y); o1.y = pack2(c2.z,c2.w);
        o1.z = pack2(d2.x,d2.y); o1.w = pack2(d2.z,d2.w);
        uint4* dst = (uint4*)&s_ac[m][cs * 16];
        dst[0] = o0; dst[1] = o1;
    }
    __syncthreads();

    // ---- P2: t[16][256] = center . Mt^T  (MFMA; B-frags straight from ws) ----
    {
        ffrag acc[4] = {fz, fz, fz, fz};
        const unsigned short* ar = &s_ac[l15][quad * 8];
        const unsigned short* b0 = wMt + (size_t)(wv*64 +  0 + l15)*256 + quad*8;
        const unsigned short* b1 = wMt + (size_t)(wv*64 + 16 + l15)*256 + quad*8;
        const unsigned short* b2 = wMt + (size_t)(wv*64 + 32 + l15)*256 + quad*8;
        const unsigned short* b3 = wMt + (size_t)(wv*64 + 48 + l15)*256 + quad*8;
        #pragma unroll
        for (int k0 = 0; k0 < 256; k0 += 32) {
            bfrag af = *(const bfrag*)(ar + k0);
            acc[0] = __builtin_amdgcn_mfma_f32_16x16x32_bf16(af, *(const bfrag*)(b0 + k0), acc[0], 0,0,0);
            acc[1] = __builtin_amdgcn_mfma_f32_16x16x32_bf16(af, *(const bfrag*)(b1 + k0), acc[1], 0,0,0);
            acc[2] = __builtin_amdgcn_mfma_f32_16x16x32_bf16(af, *(const bfrag*)(b2 + k0), acc[2], 0,0,0);
            acc[3] = __builtin_amdgcn_mfma_f32_16x16x32_bf16(af, *(const bfrag*)(b3 + k0), acc[3], 0,0,0);
        }
        #pragma unroll
        for (int t = 0; t < 4; ++t)
            #pragma unroll
            for (int r = 0; r < 4; ++r)
                s_t[quad*4 + r][wv*64 + t*16 + l15] = acc[t][r];
    }
    __syncthreads();

    // ---- P3: attention, 2 rows per chunk ----
    for (int c = 0; c < 8; ++c) {
        {   // stage 32 neighbor rows -> bf16 LDS
            int r = tid >> 3, cs = tid & 7;
            int idx = nidx[(size_t)(row0 + 2*c + (r >> 4)) * KK + (r & 15)];
            uint4* dst = (uint4*)&s_nb[r][cs * 32];
            if (TBF) {
                const uint4* src = (const uint4*)(tbl + (size_t)idx * DD + cs * 32);
                dst[0] = src[0]; dst[1] = src[1]; dst[2] = src[2]; dst[3] = src[3];
            } else {
                const float4* src = (const float4*)(embs + (size_t)idx * DD + cs * 32);
                #pragma unroll
                for (int q = 0; q < 4; ++q) {
                    float4 a = src[2*q], b = src[2*q + 1];
                    uint4 o;
                    o.x = pack2(a.x,a.y); o.y = pack2(a.z,a.w);
                    o.z = pack2(b.x,b.y); o.w = pack2(b.z,b.w);
                    dst[q] = o;
                }
            }
        }
        __syncthreads();
        {   // logits partials: (mi,k,i) each a 32-elem dot
            int mi = tid >> 7, k = (tid >> 3) & 15, i = tid & 7;
            const unsigned short* nr = &s_nb[mi*16 + k][i * 32];
            const float* tr = &s_t[2*c + mi][i * 32];
            float acc = 0.f;
            #pragma unroll
            for (int j = 0; j < 4; ++j) {
                uint4 nv = *(const uint4*)(nr + j*8);
                float4 t0 = *(const float4*)(tr + j*8);
                float4 t1 = *(const float4*)(tr + j*8 + 4);
                acc += lo2f(nv.x)*t0.x + hi2f(nv.x)*t0.y + lo2f(nv.y)*t0.z + hi2f(nv.y)*t0.w
                     + lo2f(nv.z)*t1.x + hi2f(nv.z)*t1.y + lo2f(nv.w)*t1.z + hi2f(nv.w)*t1.w;
            }
            s_red[mi*16 + k][i] = acc;
        }
        __syncthreads();
        if (tid < 32) {   // finish logits + softmax (16-lane groups)
            int mi = tid >> 4, k = tid & 15;
            float lg = 0.f;
            #pragma unroll
            for (int j = 0; j < 8; ++j) lg += s_red[tid][j];
            float w = nbw[(size_t)(row0 + 2*c + mi) * KK + k];
            lg = lg * 0.125f + logf(fmaxf(w, 1e-6f));
            float mx = lg;
            #pragma unroll
            for (int off = 8; off >= 1; off >>= 1) mx = fmaxf(mx, __shfl_xor(mx, off, 16));
            float e = expf(lg - mx);
            float s = e;
            #pragma unroll
            for (int off = 8; off >= 1; off >>= 1) s += __shfl_xor(s, off, 16);
            s_attn[tid] = e / s;
        }
        __syncthreads();
        {   // ctx: 2 cols per thread -> s_ax bf16
            int mi = tid >> 7, j = tid & 127;
            float a0 = 0.f, a1 = 0.f;
            #pragma unroll
            for (int k = 0; k < 16; ++k) {
                unsigned int v = *(const unsigned int*)&s_nb[mi*16 + k][2*j];
                float w = s_attn[mi*16 + k];
                a0 += w * lo2f(v); a1 += w * hi2f(v);
            }
            *(unsigned int*)&s_ax[2*c + mi][2*j] = pack2(a0, a1);
        }
        __syncthreads();
    }

    // ---- P4: gate = sigmoid(center.Wg^T + bg); s_ax *= gate ----
    {
        ffrag acc[4] = {fz, fz, fz, fz};
        const unsigned short* ar = &s_ac[l15][quad * 8];
        const unsigned short* b0 = wWg + (size_t)(wv*64 +  0 + l15)*256 + quad*8;
        const unsigned short* b1 = wWg + (size_t)(wv*64 + 16 + l15)*256 + quad*8;
        const unsigned short* b2 = wWg + (size_t)(wv*64 + 32 + l15)*256 + quad*8;
        const unsigned short* b3 = wWg + (size_t)(wv*64 + 48 + l15)*256 + quad*8;
        #pragma unroll
        for (int k0 = 0; k0 < 256; k0 += 32) {
            bfrag af = *(const bfrag*)(ar + k0);
            acc[0] = __builtin_amdgcn_mfma_f32_16x16x32_bf16(af, *(const bfrag*)(b0 + k0), acc[0], 0,0,0);
            acc[1] = __builtin_amdgcn_mfma_f32_16x16x32_bf16(af, *(const bfrag*)(b1 + k0), acc[1], 0,0,0);
            acc[2] = __builtin_amdgcn_mfma_f32_16x16x32_bf16(af, *(const bfrag*)(b2 + k0), acc[2], 0,0,0);
            acc[3] = __builtin_amdgcn_mfma_f32_16x16x32_bf16(af, *(const bfrag*)(b3 + k0), acc[3], 0,0,0);
        }
        #pragma unroll
        for (int t = 0; t < 4; ++t) {
            int col = wv*64 + t*16 + l15;
            float bgv = bg[col];
            #pragma unroll
            for (int r = 0; r < 4; ++r) {
                int rr = quad*4 + r;
                float g = 1.f / (1.f + expf(-(acc[t][r] + bgv)));
                unsigned short* p = &s_ax[rr][col];
                *p = f2b(bf2f(*p) * g);
            }
        }
    }
    __syncthreads();

    // ---- P5: x = [center|ctx].Wo^T + bo + center_f32 -> s_t ----
    {
        ffrag acc[4] = {fz, fz, fz, fz};
        const unsigned short* arc = &s_ac[l15][quad * 8];
        const unsigned short* arx = &s_ax[l15][quad * 8];
        const unsigned short* b0 = wWo + (size_t)(wv*64 +  0 + l15)*512 + quad*8;
        const unsigned short* b1 = wWo + (size_t)(wv*64 + 16 + l15)*512 + quad*8;
        const unsigned short* b2 = wWo + (size_t)(wv*64 + 32 + l15)*512 + quad*8;
        const unsigned short* b3 = wWo + (size_t)(wv*64 + 48 + l15)*512 + quad*8;
        #pragma unroll
        for (int k0 = 0; k0 < 256; k0 += 32) {
            bfrag af = *(const bfrag*)(arc + k0);
            acc[0] = __builtin_amdgcn_mfma_f32_16x16x32_bf16(af, *(const bfrag*)(b0 + k0), acc[0], 0,0,0);
            acc[1] = __builtin_amdgcn_mfma_f32_16x16x32_bf16(af, *(const bfrag*)(b1 + k0), acc[1], 0,0,0);
            acc[2] = __builtin_amdgcn_mfma_f32_16x16x32_bf16(af, *(const bfrag*)(b2 + k0), acc[2], 0,0,0);
            acc[3] = __builtin_amdgcn_mfma_f32_16x16x32_bf16(af, *(const bfrag*)(b3 + k0), acc[3], 0,0,0);
        }
        #pragma unroll
        for (int k0 = 0; k0 < 256; k0 += 32) {
            bfrag af = *(const bfrag*)(arx + k0);
            acc[0] = __builtin_amdgcn_mfma_f32_16x16x32_bf16(af, *(const bfrag*)(b0 + 256 + k0), acc[0], 0,0,0);
            acc[1] = __builtin_amdgcn_mfma_f32_16x16x32_bf16(af, *(const bfrag*)(b1 + 256 + k0), acc[1], 0,0,0);
            acc[2] = __builtin_amdgcn_mfma_f32_16x16x32_bf16(af, *(const bfrag*)(b2 + 256 + k0), acc[2], 0,0,0);
            acc[3] = __builtin_amdgcn_mfma_f32_16x16x32_bf16(af, *(const bfrag*)(b3 + 256 + k0), acc[3], 0,0,0);
        }
        #pragma unroll
        for (int t = 0; t < 4; ++t) {
            int col = wv*64 + t*16 + l15;
            float bov = bo[col];
            #pragma unroll
            for (int r = 0; r < 4; ++r) {
                int rr = quad*4 + r;
                float ctr = embs[(size_t)s_cidx[rr] * DD + col];  // f32 residual
                s_t[rr][col] = acc[t][r] + bov + ctr;
            }
        }
    }
    __syncthreads();

    // ---- P6: LayerNorm ----
    {
        #pragma unroll
        for (int jj = 0; jj < 4; ++jj) {
            int m = wv * 4 + jj;
            float x0 = s_t[m][lane],       x1 = s_t[m][64 + lane];
            float x2 = s_t[m][128 + lane], x3 = s_t[m][192 + lane];
            float s  = x0 + x1 + x2 + x3;
            float ss = x0*x0 + x1*x1 + x2*x2 + x3*x3;
            #pragma unroll
            for (int off = 32; off >= 1; off >>= 1) {
                s  += __shfl_xor(s, off);
                ss += __shfl_xor(ss, off);
            }
            float mu  = s * (1.f/256.f);
            float var = ss * (1.f/256.f) - mu*mu;
            float rs  = rsqrtf(var + 1e-5f);
            size_t base = (size_t)(row0 + m) * DD;
            float xs[4] = {x0, x1, x2, x3};
            #pragma unroll
            for (int cc = 0; cc < 4; ++cc) {
                int dd = cc*64 + lane;
                out[base + dd] = (xs[cc] - mu) * rs * gamma[dd] + beta[dd];
            }
        }
    }
}

// ---------------- round-2 f32 fallback (only if ws too small) ----------------
#define SD 260
#define KT 16
#define WS 17
extern "C" __global__ __launch_bounds__(256)
void na_f32_kernel(const float* __restrict__ embs, const int* __restrict__ center_idx,
                   const int* __restrict__ nb_idx, const float* __restrict__ nb_w,
                   const float* __restrict__ Wq, const float* __restrict__ Wk,
                   const float* __restrict__ Wg, const float* __restrict__ bg,
                   const float* __restrict__ Wo, const float* __restrict__ bo,
                   const float* __restrict__ gamma, const float* __restrict__ beta,
                   float* __restrict__ out)
{
    __shared__ __align__(16) float s_center[MM][SD];
    __shared__ __align__(16) float s_tc[MM][SD];
    __shared__ __align__(16) float s_nb[KK][SD];
    __shared__ __align__(16) float s_w[DD][WS];
    __shared__ __align__(16) float s_q[MM][64];
    __shared__ float s_red[KK][16];
    __shared__ float s_attn[KK];
    const int tid = threadIdx.x;
    const int row0 = blockIdx.x * MM;
    const int td = tid & 63, tm = tid >> 6;
    {
        int m = tid >> 4, c = tid & 15;
        int idx = center_idx[row0 + m];
        const float4* src = (const float4*)(embs + (size_t)idx * DD) + c * 4;
        float4* dst = (float4*)&s_center[m][c * 16];
        dst[0]=src[0]; dst[1]=src[1]; dst[2]=src[2]; dst[3]=src[3];
    }
    __syncthreads();
    {
        const int a = tid & 63, mg = tid >> 6;
        float qacc[4] = {0,0,0,0};
        for (int kt = 0; kt < DD; kt += KT) {
            __syncthreads();
            { int r = tid >> 2, c4 = (tid & 3) * 4;
              *(float4*)&s_w[r][c4] = *(const float4*)(Wq + r * DD + kt + c4); }
            __syncthreads();
            #pragma unroll
            for (int kk = 0; kk < KT; kk += 4) {
                float4 b = *(const float4*)&s_w[a][kk];
                #pragma unroll
                for (int i = 0; i < 4; ++i) {
                    float4 av = *(const float4*)&s_center[4*mg + i][kt + kk];
                    qacc[i] += av.x*b.x + av.y*b.y + av.z*b.z + av.w*b.w;
                }
            }
        }
        __syncthreads();
        #pragma unroll
        for (int i = 0; i < 4; ++i) s_q[4*mg + i][a] = qacc[i];
    }
    __syncthreads();
    {
        float tacc[4][4];
        #pragma unroll
        for (int i=0;i<4;++i) { tacc[i][0]=tacc[i][1]=tacc[i][2]=tacc[i][3]=0.f; }
        for (int kk = 0; kk < 64; kk += 4) {
            float4 bk[4];
            #pragma unroll
            for (int t4 = 0; t4 < 4; ++t4)
                bk[t4] = *(const float4*)(Wk + (size_t)(kk + t4) * DD + 4 * td);
            #pragma unroll
            for (int i = 0; i < 4; ++i) {
                float4 av = *(const float4*)&s_q[4*tm + i][kk];
                tacc[i][0] += av.x*bk[0].x + av.y*bk[1].x + av.z*bk[2].x + av.w*bk[3].x;
                tacc[i][1] += av.x*bk[0].y + av.y*bk[1].y + av.z*bk[2].y + av.w*bk[3].y;
                tacc[i][2] += av.x*bk[0].z + av.y*bk[1].z + av.z*bk[2].z + av.w*bk[3].z;
                tacc[i][3] += av.x*bk[0].w + av.y*bk[1].w + av.z*bk[2].w + av.w*bk[3].w;
            }
        }
        #pragma unroll
        for (int i = 0; i < 4; ++i)
            *(float4*)&s_tc[4*tm + i][4*td] = make_float4(tacc[i][0],tacc[i][1],tacc[i][2],tacc[i][3]);
    }
    __syncthreads();
    for (int m = 0; m < MM; ++m) {
        { int k = tid >> 4, c = tid & 15;
          int idx = nb_idx[(row0 + m) * KK + k];
          const float4* src = (const float4*)(embs + (size_t)idx * DD) + c * 4;
          float4* dst = (float4*)&s_nb[k][c * 16];
          dst[0]=src[0]; dst[1]=src[1]; dst[2]=src[2]; dst[3]=src[3]; }
        __syncthreads();
        { int k = tid >> 4, i = tid & 15;
          float acc = 0.f;
          #pragma unroll
          for (int j4 = 0; j4 < 4; ++j4) {
              float4 nv = *(const float4*)&s_nb[k][i*16 + 4*j4];
              float4 tv = *(const float4*)&s_tc[m][i*16 + 4*j4];
              acc += nv.x*tv.x + nv.y*tv.y + nv.z*tv.z + nv.w*tv.w;
          }
          s_red[k][i] = acc; }
        __syncthreads();
        if (tid < KK) {
            float lg = 0.f;
            #pragma unroll
            for (int i = 0; i < 16; ++i) lg += s_red[tid][i];
            float wv2 = nb_w[(row0 + m) * KK + tid];
            lg = lg * 0.125f + logf(fmaxf(wv2, 1e-6f));
            float mx = lg;
            #pragma unroll
            for (int off = 8; off >= 1; off >>= 1) mx = fmaxf(mx, __shfl_xor(mx, off));
            float e = expf(lg - mx);
            float s = e;
            #pragma unroll
            for (int off = 8; off >= 1; off >>= 1) s += __shfl_xor(s, off);
            s_attn[tid] = e / s;
        }
        __syncthreads();
        { float acc = 0.f;
          #pragma unroll
          for (int k = 0; k < KK; ++k) acc += s_attn[k] * s_nb[k][tid];
          s_tc[m][tid] = acc; }
        __syncthreads();
    }
    {
        float acc[4][4];
        #pragma unroll
        for (int i=0;i<4;++i){acc[i][0]=acc[i][1]=acc[i][2]=acc[i][3]=0.f;}
        for (int kt = 0; kt < DD; kt += KT) {
            __syncthreads();
            #pragma unroll
            for (int j = 0; j < 4; ++j) {
                int r = (tid >> 2) + 64 * j, c4 = (tid & 3) * 4;
                *(float4*)&s_w[r][c4] = *(const float4*)(Wg + (size_t)r * DD + kt + c4);
            }
            __syncthreads();
            #pragma unroll
            for (int kk = 0; kk < KT; kk += 4) {
                float4 b[4];
                #pragma unroll
                for (int j = 0; j < 4; ++j) b[j] = *(const float4*)&s_w[4*td + j][kk];
                #pragma unroll
                for (int i = 0; i < 4; ++i) {
                    float4 av = *(const float4*)&s_center[4*tm + i][kt + kk];
                    #pragma unroll
                    for (int j = 0; j < 4; ++j)
                        acc[i][j] += av.x*b[j].x + av.y*b[j].y + av.z*b[j].z + av.w*b[j].w;
                }
            }
        }
        float bgv[4];
        #pragma unroll
        for (int j = 0; j < 4; ++j) bgv[j] = bg[4*td + j];
        __syncthreads();
        #pragma unroll
        for (int i = 0; i < 4; ++i)
            #pragma unroll
            for (int j = 0; j < 4; ++j) {
                float g = 1.f / (1.f + expf(-(acc[i][j] + bgv[j])));
                s_tc[4*tm + i][4*td + j] *= g;
            }
    }
    {
        float acc[4][4];
        #pragma unroll
        for (int i=0;i<4;++i){acc[i][0]=acc[i][1]=acc[i][2]=acc[i][3]=0.f;}
        for (int kt = 0; kt < 2*DD; kt += KT) {
            __syncthreads();
            #pragma unroll
            for (int j = 0; j < 4; ++j) {
                int r = (tid >> 2) + 64 * j, c4 = (tid & 3) * 4;
                *(float4*)&s_w[r][c4] = *(const float4*)(Wo + (size_t)r * 2 * DD + kt + c4);
            }
            __syncthreads();
            const float* Abase = (kt < DD) ? &s_center[0][0] : &s_tc[0][0];
            const int kb = (kt < DD) ? kt : kt - DD;
            #pragma unroll
            for (int kk = 0; kk < KT; kk += 4) {
                float4 b[4];
                #pragma unroll
                for (int j = 0; j < 4; ++j) b[j] = *(const float4*)&s_w[4*td + j][kk];
                #pragma unroll
                for (int i = 0; i < 4; ++i) {
                    float4 av = *(const float4*)(Abase + (4*tm + i) * SD + kb + kk);
                    #pragma unroll
                    for (int j = 0; j < 4; ++j)
                        acc[i][j] += av.x*b[j].x + av.y*b[j].y + av.z*b[j].z + av.w*b[j].w;
                }
            }
        }
        float bov[4];
        #pragma unroll
        for (int j = 0; j < 4; ++j) bov[j] = bo[4*td + j];
        __syncthreads();
        #pragma unroll
        for (int i = 0; i < 4; ++i)
            #pragma unroll
            for (int j = 0; j < 4; ++j)
                s_tc[4*tm + i][4*td + j] = acc[i][j] + bov[j] + s_center[4*tm + i][4*td + j];
    }
    __syncthreads();
    {
        int wv2 = tid >> 6, lane = tid & 63;
        #pragma unroll
        for (int jj = 0; jj < 4; ++jj) {
            int m = wv2 * 4 + jj;
            float x0 = s_tc[m][lane],       x1 = s_tc[m][64 + lane];
            float x2 = s_tc[m][128 + lane], x3 = s_tc[m][192 + lane];
            float s  = x0+x1+x2+x3;
            float ss = x0*x0 + x1*x1 + x2*x2 + x3*x3;
            #pragma unroll
            for (int off = 32; off >= 1; off >>= 1) { s += __shfl_xor(s, off); ss += __shfl_xor(ss, off); }
            float mu = s * (1.f/256.f);
            float var = ss * (1.f/256.f) - mu*mu;
            float rs = rsqrtf(var + 1e-5f);
            size_t base = (size_t)(row0 + m) * DD;
            float xs[4] = {x0,x1,x2,x3};
            #pragma unroll
            for (int c = 0; c < 4; ++c) {
                int dd = c*64 + lane;
                out[base + dd] = (xs[c] - mu) * rs * gamma[dd] + beta[dd];
            }
        }
    }
}

extern "C" void kernel_launch(void* const* d_in, const int* in_sizes, int n_in,
                              void* d_out, int out_size, void* d_ws, size_t ws_size,
                              hipStream_t stream) {
    const float* embs  = (const float*)d_in[0];
    const int*   cidx  = (const int*)d_in[1];
    const int*   nidx  = (const int*)d_in[2];
    const float* nbw   = (const float*)d_in[3];
    const float* Wq    = (const float*)d_in[4];
    const float* Wk    = (const float*)d_in[5];
    const float* Wg    = (const float*)d_in[6];
    const float* bg    = (const float*)d_in[7];
    const float* Wo    = (const float*)d_in[8];
    const float* bo    = (const float*)d_in[9];
    const float* gamma = (const float*)d_in[10];
    const float* beta  = (const float*)d_in[11];
    float* out = (float*)d_out;

    const int B = in_sizes[1];
    const int nemb = in_sizes[0];
    const size_t need_w = 262144 * 2;                       // weights bf16
    const size_t need_t = need_w + (size_t)nemb * 2;        // + table bf16

    if (ws_size < need_w) {
        hipLaunchKernelGGL(na_f32_kernel, dim3(B / MM), dim3(256), 0, stream,
                           embs, cidx, nidx, nbw, Wq, Wk, Wg, bg, Wo, bo, gamma, beta, out);
        return;
    }
    unsigned short* wsb = (unsigned short*)d_ws;
    hipLaunchKernelGGL(prep_weights, dim3(768), dim3(256), 0, stream, Wq, Wk, Wg, Wo, wsb);

    if (ws_size >= need_t && (nemb & 7) == 0) {
        int n8 = nemb / 8;
        hipLaunchKernelGGL(cvt_table, dim3((n8 + 255) / 256), dim3(256), 0, stream,
                           embs, wsb + 262144, n8);
        hipLaunchKernelGGL(na_mfma_kernel<true>, dim3(B / MM), dim3(256), 0, stream,
                           embs, cidx, nidx, nbw, wsb + 262144, wsb, wsb + 65536, wsb + 131072,
                           bg, bo, gamma, beta, out);
    } else {
        hipLaunchKernelGGL(na_mfma_kernel<false>, dim3(B / MM), dim3(256), 0, stream,
                           embs, cidx, nidx, nbw, (const unsigned short*)nullptr,
                           wsb, wsb + 65536, wsb + 131072,
                           bg, bo, gamma, beta, out);
    }
}

// Round 4
// 264.426 us; speedup vs baseline: 2.5967x; 1.0169x over previous
//
#include <hip/hip_runtime.h>

#define DD 256
#define MM 16

typedef __attribute__((ext_vector_type(8))) short bfrag;   // 8 bf16 (4 VGPRs)
typedef __attribute__((ext_vector_type(4))) float ffrag;   // 4 f32 acc

__device__ __forceinline__ float lo2f(unsigned int p){ union{unsigned int i; float f;} v; v.i = p<<16; return v.f; }
__device__ __forceinline__ float hi2f(unsigned int p){ union{unsigned int i; float f;} v; v.i = p & 0xffff0000u; return v.f; }
__device__ __forceinline__ float bf2f(unsigned short u){ union{unsigned int i; float f;} v; v.i = ((unsigned int)u)<<16; return v.f; }
__device__ __forceinline__ unsigned short f2b(float x){            // RNE bf16
    union{float f; unsigned int i;} v; v.f = x;
    unsigned int r = v.i + 0x7fffu + ((v.i>>16)&1u);
    return (unsigned short)(r>>16);
}
__device__ __forceinline__ unsigned int pack2(float a, float b){
    return (unsigned int)f2b(a) | ((unsigned int)f2b(b)<<16);
}

// ---------------- single merged prepass ----------------
// ws layout (bf16): [0,65536) Mt=Wq^T*Wk; [65536,131072) Wg; [131072,262144) Wo; [262144,...) bf16 table
extern "C" __global__ __launch_bounds__(256)
void prep_all(const float* __restrict__ Wq, const float* __restrict__ Wk,
              const float* __restrict__ Wg, const float* __restrict__ Wo,
              const float* __restrict__ embs, unsigned short* __restrict__ ws, int n8)
{
    int bid = blockIdx.x, e = threadIdx.x;
    if (bid < 256) {
        float acc = 0.f;
        #pragma unroll 8
        for (int a = 0; a < 64; ++a) acc = fmaf(Wq[a*256 + e], Wk[a*256 + bid], acc);
        ws[bid*256 + e] = f2b(acc);
    } else if (bid < 512) {
        int r = bid - 256;
        ws[65536 + r*256 + e] = f2b(Wg[r*256 + e]);
    } else if (bid < 768) {
        int r = bid - 512;
        ws[131072 + r*512 + e]       = f2b(Wo[r*512 + e]);
        ws[131072 + r*512 + 256 + e] = f2b(Wo[r*512 + 256 + e]);
    } else {
        int i = (bid - 768)*256 + e;
        if (i < n8) {
            const float4* s = (const float4*)embs + (size_t)i*2;
            float4 a = s[0], b = s[1];
            uint4 o;
            o.x = pack2(a.x,a.y); o.y = pack2(a.z,a.w);
            o.z = pack2(b.x,b.y); o.w = pack2(b.z,b.w);
            ((uint4*)(ws + 262144))[i] = o;
        }
    }
}

template<bool TBF>
__device__ __forceinline__ void gather8(uint4* buf, const unsigned short* tbl,
                                        const float* embs, int idx, int p)
{
    if (TBF) {
        const uint4* s = (const uint4*)(tbl + (size_t)idx*DD) + p*8;
        #pragma unroll
        for (int i = 0; i < 8; ++i) buf[i] = s[i];
    } else {
        const float4* s = (const float4*)(embs + (size_t)idx*DD) + p*16;
        #pragma unroll
        for (int i = 0; i < 8; ++i) {
            float4 a = s[2*i], b = s[2*i + 1];
            buf[i].x = pack2(a.x,a.y); buf[i].y = pack2(a.z,a.w);
            buf[i].z = pack2(b.x,b.y); buf[i].w = pack2(b.z,b.w);
        }
    }
}

// ---------------- main fused kernel: 4 barriers total ----------------
template<bool TBF>
__global__ __launch_bounds__(256, 2)
void na_mfma2(const float* __restrict__ embs,
              const int* __restrict__ cidx,
              const int* __restrict__ nidx,
              const float* __restrict__ nbw,
              const unsigned short* __restrict__ tbl,
              const unsigned short* __restrict__ wMt,
              const unsigned short* __restrict__ wWg,
              const unsigned short* __restrict__ wWo,
              const float* __restrict__ bg,
              const float* __restrict__ bo,
              const float* __restrict__ gamma,
              const float* __restrict__ beta,
              float* __restrict__ out)
{
    __shared__ __align__(16) unsigned short s_ac[16][264];    // center bf16 (A-frags)
    __shared__ __align__(16) unsigned short s_ax[16][264];    // gate bf16 -> gated ctx bf16
    __shared__ __align__(16) float s_t[16][260];              // t f32 -> x f32
    __shared__ __align__(16) unsigned short s_nb[4][16][264]; // per-wave neighbor staging
    __shared__ float s_attn[4][16];
    __shared__ int   s_cidx[16];

    const int tid  = threadIdx.x;
    const int row0 = blockIdx.x * MM;
    const int lane = tid & 63, wv = tid >> 6;
    const int l15  = lane & 15, quad = lane >> 4;
    const ffrag fz = {0.f, 0.f, 0.f, 0.f};

    // ---- P1: stage 16 center rows (f32 -> bf16) ----
    if (tid < 16) s_cidx[tid] = cidx[row0 + tid];
    {
        int m = tid >> 4, cs = tid & 15;
        int idx = cidx[row0 + m];
        const float4* src = (const float4*)(embs + (size_t)idx * DD + cs * 16);
        float4 a = src[0], b = src[1], c2 = src[2], d2 = src[3];
        uint4 o0, o1;
        o0.x = pack2(a.x,a.y);   o0.y = pack2(a.z,a.w);
        o0.z = pack2(b.x,b.y);   o0.w = pack2(b.z,b.w);
        o1.x = pack2(c2.x,c2.y); o1.y = pack2(c2.z,c2.w);
        o1.z = pack2(d2.x,d2.y); o1.w = pack2(d2.z,d2.w);
        uint4* dst = (uint4*)&s_ac[m][cs * 16];
        dst[0] = o0; dst[1] = o1;
    }
    __syncthreads();

    // ---- P2: t = center.Mt^T (f32 -> s_t) AND gate = sigmoid(center.Wg^T+bg) (bf16 -> s_ax) ----
    {
        ffrag at[4] = {fz,fz,fz,fz}, ag[4] = {fz,fz,fz,fz};
        const unsigned short* ar = &s_ac[l15][quad * 8];
        const unsigned short* bt[4];
        const unsigned short* bgq[4];
        #pragma unroll
        for (int t = 0; t < 4; ++t) {
            bt[t]  = wMt + (size_t)(wv*64 + t*16 + l15)*256 + quad*8;
            bgq[t] = wWg + (size_t)(wv*64 + t*16 + l15)*256 + quad*8;
        }
        #pragma unroll
        for (int k0 = 0; k0 < 256; k0 += 32) {
            bfrag af = *(const bfrag*)(ar + k0);
            #pragma unroll
            for (int t = 0; t < 4; ++t) {
                at[t] = __builtin_amdgcn_mfma_f32_16x16x32_bf16(af, *(const bfrag*)(bt[t]  + k0), at[t], 0,0,0);
                ag[t] = __builtin_amdgcn_mfma_f32_16x16x32_bf16(af, *(const bfrag*)(bgq[t] + k0), ag[t], 0,0,0);
            }
        }
        #pragma unroll
        for (int t = 0; t < 4; ++t) {
            int col = wv*64 + t*16 + l15;
            float bgv = bg[col];
            #pragma unroll
            for (int r = 0; r < 4; ++r) {
                int rr = quad*4 + r;
                s_t[rr][col] = at[t][r];
                float g = 1.f / (1.f + expf(-(ag[t][r] + bgv)));
                s_ax[rr][col] = f2b(g);
            }
        }
    }
    __syncthreads();

    // ---- P3: attention, per-wave, barrier-free, prefetched ----
    {
        const int k = lane >> 2;   // neighbor 0..15
        const int p = lane & 3;    // col quarter: cols [64p, 64p+64)
        int idxs[4];
        #pragma unroll
        for (int j = 0; j < 4; ++j)
            idxs[j] = nidx[(size_t)(row0 + 4*wv + j) * 16 + k];

        uint4 buf[2][8];
        gather8<TBF>(buf[0], tbl, embs, idxs[0], p);

        #pragma unroll
        for (int j = 0; j < 4; ++j) {
            if (j < 3) gather8<TBF>(buf[(j+1)&1], tbl, embs, idxs[j+1], p);
            const int m = 4*wv + j;
            // stage row j's neighbors (for the ctx pass)
            unsigned short* nbp = &s_nb[wv][k][p*64];
            #pragma unroll
            for (int i = 0; i < 8; ++i) *(uint4*)(nbp + i*8) = buf[j&1][i];
            // logits partial straight from the prefetch registers
            const float* trow = &s_t[m][p*64];
            float part = 0.f;
            #pragma unroll
            for (int i = 0; i < 8; ++i) {
                uint4 v = buf[j&1][i];
                float4 t0 = *(const float4*)(trow + i*8);
                float4 t1 = *(const float4*)(trow + i*8 + 4);
                part += lo2f(v.x)*t0.x + hi2f(v.x)*t0.y + lo2f(v.y)*t0.z + hi2f(v.y)*t0.w
                      + lo2f(v.z)*t1.x + hi2f(v.z)*t1.y + lo2f(v.w)*t1.z + hi2f(v.w)*t1.w;
            }
            part += __shfl_xor(part, 1);
            part += __shfl_xor(part, 2);
            float wgt = nbw[(size_t)(row0 + m) * 16 + k];
            float lg = part * 0.125f + logf(fmaxf(wgt, 1e-6f));
            float mx = lg;
            mx = fmaxf(mx, __shfl_xor(mx, 4));  mx = fmaxf(mx, __shfl_xor(mx, 8));
            mx = fmaxf(mx, __shfl_xor(mx, 16)); mx = fmaxf(mx, __shfl_xor(mx, 32));
            float e = expf(lg - mx);
            float s = e;
            s += __shfl_xor(s, 4);  s += __shfl_xor(s, 8);
            s += __shfl_xor(s, 16); s += __shfl_xor(s, 32);
            float attn = e / s;
            if (p == 0) s_attn[wv][k] = attn;
            // ctx: lane owns cols [4*lane, 4*lane+4); gate applied inline
            float4 aw0 = *(const float4*)&s_attn[wv][0];
            float4 aw1 = *(const float4*)&s_attn[wv][4];
            float4 aw2 = *(const float4*)&s_attn[wv][8];
            float4 aw3 = *(const float4*)&s_attn[wv][12];
            float aarr[16] = {aw0.x,aw0.y,aw0.z,aw0.w, aw1.x,aw1.y,aw1.z,aw1.w,
                              aw2.x,aw2.y,aw2.z,aw2.w, aw3.x,aw3.y,aw3.z,aw3.w};
            float c0=0.f, c1=0.f, c2=0.f, c3=0.f;
            #pragma unroll
            for (int kk = 0; kk < 16; ++kk) {
                uint2 v = *(const uint2*)&s_nb[wv][kk][lane*4];
                float a = aarr[kk];
                c0 += a * lo2f(v.x); c1 += a * hi2f(v.x);
                c2 += a * lo2f(v.y); c3 += a * hi2f(v.y);
            }
            uint2 g = *(const uint2*)&s_ax[m][lane*4];
            c0 *= lo2f(g.x); c1 *= hi2f(g.x); c2 *= lo2f(g.y); c3 *= hi2f(g.y);
            uint2 o; o.x = pack2(c0, c1); o.y = pack2(c2, c3);
            *(uint2*)&s_ax[m][lane*4] = o;
        }
    }
    __syncthreads();

    // ---- P5: x = [center|gated ctx].Wo^T + bo + center_f32 -> s_t ----
    {
        ffrag acc[4] = {fz,fz,fz,fz};
        const unsigned short* arc = &s_ac[l15][quad * 8];
        const unsigned short* arx = &s_ax[l15][quad * 8];
        const unsigned short* b[4];
        #pragma unroll
        for (int t = 0; t < 4; ++t)
            b[t] = wWo + (size_t)(wv*64 + t*16 + l15)*512 + quad*8;
        #pragma unroll
        for (int k0 = 0; k0 < 256; k0 += 32) {
            bfrag af = *(const bfrag*)(arc + k0);
            #pragma unroll
            for (int t = 0; t < 4; ++t)
                acc[t] = __builtin_amdgcn_mfma_f32_16x16x32_bf16(af, *(const bfrag*)(b[t] + k0), acc[t], 0,0,0);
        }
        #pragma unroll
        for (int k0 = 0; k0 < 256; k0 += 32) {
            bfrag af = *(const bfrag*)(arx + k0);
            #pragma unroll
            for (int t = 0; t < 4; ++t)
                acc[t] = __builtin_amdgcn_mfma_f32_16x16x32_bf16(af, *(const bfrag*)(b[t] + 256 + k0), acc[t], 0,0,0);
        }
        #pragma unroll
        for (int t = 0; t < 4; ++t) {
            int col = wv*64 + t*16 + l15;
            float bov = bo[col];
            #pragma unroll
            for (int r = 0; r < 4; ++r) {
                int rr = quad*4 + r;
                float ctr = embs[(size_t)s_cidx[rr] * DD + col];  // f32 residual
                s_t[rr][col] = acc[t][r] + bov + ctr;             // t is dead; overwrite with x
            }
        }
    }
    __syncthreads();

    // ---- P6: LayerNorm ----
    {
        #pragma unroll
        for (int jj = 0; jj < 4; ++jj) {
            int m = wv * 4 + jj;
            float x0 = s_t[m][lane],       x1 = s_t[m][64 + lane];
            float x2 = s_t[m][128 + lane], x3 = s_t[m][192 + lane];
            float s  = x0 + x1 + x2 + x3;
            float ss = x0*x0 + x1*x1 + x2*x2 + x3*x3;
            #pragma unroll
            for (int off = 32; off >= 1; off >>= 1) {
                s  += __shfl_xor(s, off);
                ss += __shfl_xor(ss, off);
            }
            float mu  = s * (1.f/256.f);
            float var = ss * (1.f/256.f) - mu*mu;
            float rs  = rsqrtf(var + 1e-5f);
            size_t base = (size_t)(row0 + m) * DD;
            float xs[4] = {x0, x1, x2, x3};
            #pragma unroll
            for (int cc = 0; cc < 4; ++cc) {
                int dd = cc*64 + lane;
                out[base + dd] = (xs[cc] - mu) * rs * gamma[dd] + beta[dd];
            }
        }
    }
}

// ---------------- f32 fallback (only if ws too small) ----------------
#define SD 260
#define KT 16
#define WS 17
extern "C" __global__ __launch_bounds__(256)
void na_f32_kernel(const float* __restrict__ embs, const int* __restrict__ center_idx,
                   const int* __restrict__ nb_idx, const float* __restrict__ nb_w,
                   const float* __restrict__ Wq, const float* __restrict__ Wk,
                   const float* __restrict__ Wg, const float* __restrict__ bg,
                   const float* __restrict__ Wo, const float* __restrict__ bo,
                   const float* __restrict__ gamma, const float* __restrict__ beta,
                   float* __restrict__ out)
{
    __shared__ __align__(16) float s_center[MM][SD];
    __shared__ __align__(16) float s_tc[MM][SD];
    __shared__ __align__(16) float s_nb[16][SD];
    __shared__ __align__(16) float s_w[DD][WS];
    __shared__ __align__(16) float s_q[MM][64];
    __shared__ float s_red[16][16];
    __shared__ float s_attn[16];
    const int tid = threadIdx.x;
    const int row0 = blockIdx.x * MM;
    const int td = tid & 63, tm = tid >> 6;
    {
        int m = tid >> 4, c = tid & 15;
        int idx = center_idx[row0 + m];
        const float4* src = (const float4*)(embs + (size_t)idx * DD) + c * 4;
        float4* dst = (float4*)&s_center[m][c * 16];
        dst[0]=src[0]; dst[1]=src[1]; dst[2]=src[2]; dst[3]=src[3];
    }
    __syncthreads();
    {
        const int a = tid & 63, mg = tid >> 6;
        float qacc[4] = {0,0,0,0};
        for (int kt = 0; kt < DD; kt += KT) {
            __syncthreads();
            { int r = tid >> 2, c4 = (tid & 3) * 4;
              *(float4*)&s_w[r][c4] = *(const float4*)(Wq + r * DD + kt + c4); }
            __syncthreads();
            #pragma unroll
            for (int kk = 0; kk < KT; kk += 4) {
                float4 b = *(const float4*)&s_w[a][kk];
                #pragma unroll
                for (int i = 0; i < 4; ++i) {
                    float4 av = *(const float4*)&s_center[4*mg + i][kt + kk];
                    qacc[i] += av.x*b.x + av.y*b.y + av.z*b.z + av.w*b.w;
                }
            }
        }
        __syncthreads();
        #pragma unroll
        for (int i = 0; i < 4; ++i) s_q[4*mg + i][a] = qacc[i];
    }
    __syncthreads();
    {
        float tacc[4][4];
        #pragma unroll
        for (int i=0;i<4;++i) { tacc[i][0]=tacc[i][1]=tacc[i][2]=tacc[i][3]=0.f; }
        for (int kk = 0; kk < 64; kk += 4) {
            float4 bk[4];
            #pragma unroll
            for (int t4 = 0; t4 < 4; ++t4)
                bk[t4] = *(const float4*)(Wk + (size_t)(kk + t4) * DD + 4 * td);
            #pragma unroll
            for (int i = 0; i < 4; ++i) {
                float4 av = *(const float4*)&s_q[4*tm + i][kk];
                tacc[i][0] += av.x*bk[0].x + av.y*bk[1].x + av.z*bk[2].x + av.w*bk[3].x;
                tacc[i][1] += av.x*bk[0].y + av.y*bk[1].y + av.z*bk[2].y + av.w*bk[3].y;
                tacc[i][2] += av.x*bk[0].z + av.y*bk[1].z + av.z*bk[2].z + av.w*bk[3].z;
                tacc[i][3] += av.x*bk[0].w + av.y*bk[1].w + av.z*bk[2].w + av.w*bk[3].w;
            }
        }
        #pragma unroll
        for (int i = 0; i < 4; ++i)
            *(float4*)&s_tc[4*tm + i][4*td] = make_float4(tacc[i][0],tacc[i][1],tacc[i][2],tacc[i][3]);
    }
    __syncthreads();
    for (int m = 0; m < MM; ++m) {
        { int k = tid >> 4, c = tid & 15;
          int idx = nb_idx[(row0 + m) * 16 + k];
          const float4* src = (const float4*)(embs + (size_t)idx * DD) + c * 4;
          float4* dst = (float4*)&s_nb[k][c * 16];
          dst[0]=src[0]; dst[1]=src[1]; dst[2]=src[2]; dst[3]=src[3]; }
        __syncthreads();
        { int k = tid >> 4, i = tid & 15;
          float acc = 0.f;
          #pragma unroll
          for (int j4 = 0; j4 < 4; ++j4) {
              float4 nv = *(const float4*)&s_nb[k][i*16 + 4*j4];
              float4 tv = *(const float4*)&s_tc[m][i*16 + 4*j4];
              acc += nv.x*tv.x + nv.y*tv.y + nv.z*tv.z + nv.w*tv.w;
          }
          s_red[k][i] = acc; }
        __syncthreads();
        if (tid < 16) {
            float lg = 0.f;
            #pragma unroll
            for (int i = 0; i < 16; ++i) lg += s_red[tid][i];
            float wv2 = nb_w[(row0 + m) * 16 + tid];
            lg = lg * 0.125f + logf(fmaxf(wv2, 1e-6f));
            float mx = lg;
            #pragma unroll
            for (int off = 8; off >= 1; off >>= 1) mx = fmaxf(mx, __shfl_xor(mx, off));
            float e = expf(lg - mx);
            float s = e;
            #pragma unroll
            for (int off = 8; off >= 1; off >>= 1) s += __shfl_xor(s, off);
            s_attn[tid] = e / s;
        }
        __syncthreads();
        { float acc = 0.f;
          #pragma unroll
          for (int k = 0; k < 16; ++k) acc += s_attn[k] * s_nb[k][tid];
          s_tc[m][tid] = acc; }
        __syncthreads();
    }
    {
        float acc[4][4];
        #pragma unroll
        for (int i=0;i<4;++i){acc[i][0]=acc[i][1]=acc[i][2]=acc[i][3]=0.f;}
        for (int kt = 0; kt < DD; kt += KT) {
            __syncthreads();
            #pragma unroll
            for (int j = 0; j < 4; ++j) {
                int r = (tid >> 2) + 64 * j, c4 = (tid & 3) * 4;
                *(float4*)&s_w[r][c4] = *(const float4*)(Wg + (size_t)r * DD + kt + c4);
            }
            __syncthreads();
            #pragma unroll
            for (int kk = 0; kk < KT; kk += 4) {
                float4 b[4];
                #pragma unroll
                for (int j = 0; j < 4; ++j) b[j] = *(const float4*)&s_w[4*td + j][kk];
                #pragma unroll
                for (int i = 0; i < 4; ++i) {
                    float4 av = *(const float4*)&s_center[4*tm + i][kt + kk];
                    #pragma unroll
                    for (int j = 0; j < 4; ++j)
                        acc[i][j] += av.x*b[j].x + av.y*b[j].y + av.z*b[j].z + av.w*b[j].w;
                }
            }
        }
        float bgv[4];
        #pragma unroll
        for (int j = 0; j < 4; ++j) bgv[j] = bg[4*td + j];
        __syncthreads();
        #pragma unroll
        for (int i = 0; i < 4; ++i)
            #pragma unroll
            for (int j = 0; j < 4; ++j) {
                float g = 1.f / (1.f + expf(-(acc[i][j] + bgv[j])));
                s_tc[4*tm + i][4*td + j] *= g;
            }
    }
    {
        float acc[4][4];
        #pragma unroll
        for (int i=0;i<4;++i){acc[i][0]=acc[i][1]=acc[i][2]=acc[i][3]=0.f;}
        for (int kt = 0; kt < 2*DD; kt += KT) {
            __syncthreads();
            #pragma unroll
            for (int j = 0; j < 4; ++j) {
                int r = (tid >> 2) + 64 * j, c4 = (tid & 3) * 4;
                *(float4*)&s_w[r][c4] = *(const float4*)(Wo + (size_t)r * 2 * DD + kt + c4);
            }
            __syncthreads();
            const float* Abase = (kt < DD) ? &s_center[0][0] : &s_tc[0][0];
            const int kb = (kt < DD) ? kt : kt - DD;
            #pragma unroll
            for (int kk = 0; kk < KT; kk += 4) {
                float4 b[4];
                #pragma unroll
                for (int j = 0; j < 4; ++j) b[j] = *(const float4*)&s_w[4*td + j][kk];
                #pragma unroll
                for (int i = 0; i < 4; ++i) {
                    float4 av = *(const float4*)(Abase + (4*tm + i) * SD + kb + kk);
                    #pragma unroll
                    for (int j = 0; j < 4; ++j)
                        acc[i][j] += av.x*b[j].x + av.y*b[j].y + av.z*b[j].z + av.w*b[j].w;
                }
            }
        }
        float bov[4];
        #pragma unroll
        for (int j = 0; j < 4; ++j) bov[j] = bo[4*td + j];
        __syncthreads();
        #pragma unroll
        for (int i = 0; i < 4; ++i)
            #pragma unroll
            for (int j = 0; j < 4; ++j)
                s_tc[4*tm + i][4*td + j] = acc[i][j] + bov[j] + s_center[4*tm + i][4*td + j];
    }
    __syncthreads();
    {
        int wv2 = tid >> 6, lane = tid & 63;
        #pragma unroll
        for (int jj = 0; jj < 4; ++jj) {
            int m = wv2 * 4 + jj;
            float x0 = s_tc[m][lane],       x1 = s_tc[m][64 + lane];
            float x2 = s_tc[m][128 + lane], x3 = s_tc[m][192 + lane];
            float s  = x0+x1+x2+x3;
            float ss = x0*x0 + x1*x1 + x2*x2 + x3*x3;
            #pragma unroll
            for (int off = 32; off >= 1; off >>= 1) { s += __shfl_xor(s, off); ss += __shfl_xor(ss, off); }
            float mu = s * (1.f/256.f);
            float var = ss * (1.f/256.f) - mu*mu;
            float rs = rsqrtf(var + 1e-5f);
            size_t base = (size_t)(row0 + m) * DD;
            float xs[4] = {x0,x1,x2,x3};
            #pragma unroll
            for (int c = 0; c < 4; ++c) {
                int dd = c*64 + lane;
                out[base + dd] = (xs[c] - mu) * rs * gamma[dd] + beta[dd];
            }
        }
    }
}

extern "C" void kernel_launch(void* const* d_in, const int* in_sizes, int n_in,
                              void* d_out, int out_size, void* d_ws, size_t ws_size,
                              hipStream_t stream) {
    const float* embs  = (const float*)d_in[0];
    const int*   cidx  = (const int*)d_in[1];
    const int*   nidx  = (const int*)d_in[2];
    const float* nbw   = (const float*)d_in[3];
    const float* Wq    = (const float*)d_in[4];
    const float* Wk    = (const float*)d_in[5];
    const float* Wg    = (const float*)d_in[6];
    const float* bg    = (const float*)d_in[7];
    const float* Wo    = (const float*)d_in[8];
    const float* bo    = (const float*)d_in[9];
    const float* gamma = (const float*)d_in[10];
    const float* beta  = (const float*)d_in[11];
    float* out = (float*)d_out;

    const int B = in_sizes[1];
    const int nemb = in_sizes[0];
    const size_t need_w = 262144 * 2;
    const size_t need_t = need_w + (size_t)nemb * 2;

    if (ws_size < need_w) {
        hipLaunchKernelGGL(na_f32_kernel, dim3(B / MM), dim3(256), 0, stream,
                           embs, cidx, nidx, nbw, Wq, Wk, Wg, bg, Wo, bo, gamma, beta, out);
        return;
    }
    unsigned short* wsb = (unsigned short*)d_ws;
    const bool use_tbl = (ws_size >= need_t) && ((nemb & 7) == 0);
    const int n8 = use_tbl ? (nemb / 8) : 0;
    const int prep_grid = 768 + (use_tbl ? (n8 + 255) / 256 : 0);
    hipLaunchKernelGGL(prep_all, dim3(prep_grid), dim3(256), 0, stream,
                       Wq, Wk, Wg, Wo, embs, wsb, n8);

    if (use_tbl) {
        hipLaunchKernelGGL(na_mfma2<true>, dim3(B / MM), dim3(256), 0, stream,
                           embs, cidx, nidx, nbw, wsb + 262144,
                           wsb, wsb + 65536, wsb + 131072,
                           bg, bo, gamma, beta, out);
    } else {
        hipLaunchKernelGGL(na_mfma2<false>, dim3(B / MM), dim3(256), 0, stream,
                           embs, cidx, nidx, nbw, (const unsigned short*)nullptr,
                           wsb, wsb + 65536, wsb + 131072,
                           bg, bo, gamma, beta, out);
    }
}

// Round 5
// 191.536 us; speedup vs baseline: 3.5848x; 1.3806x over previous
//
#include <hip/hip_runtime.h>

#define DD 256
#define MM 16

typedef __attribute__((ext_vector_type(8))) short bfrag;   // 8 bf16 (4 VGPRs)
typedef __attribute__((ext_vector_type(4))) float ffrag;   // 4 f32 acc

__device__ __forceinline__ float lo2f(unsigned int p){ union{unsigned int i; float f;} v; v.i = p<<16; return v.f; }
__device__ __forceinline__ float hi2f(unsigned int p){ union{unsigned int i; float f;} v; v.i = p & 0xffff0000u; return v.f; }
__device__ __forceinline__ float bf2f(unsigned short u){ union{unsigned int i; float f;} v; v.i = ((unsigned int)u)<<16; return v.f; }
__device__ __forceinline__ unsigned short f2b(float x){            // RNE bf16
    union{float f; unsigned int i;} v; v.f = x;
    unsigned int r = v.i + 0x7fffu + ((v.i>>16)&1u);
    return (unsigned short)(r>>16);
}
__device__ __forceinline__ unsigned int pack2(float a, float b){
    return (unsigned int)f2b(a) | ((unsigned int)f2b(b)<<16);
}

// Swizzled weight layout: frag id = ((colblk*KC + kchunk)*64 + lane)*8 + j
// lane = quad*16 + l15; element = W[colblk*16 + l15][kchunk*32 + quad*8 + j]
// => a wave's B-frag load is 64 lanes x contiguous 16B = one coalesced 1KB read.
__device__ __forceinline__ int swz256(int d, int e){
    return ((d>>4)*8 + (e>>5))*512 + (((e>>3)&3)*16 + (d&15))*8 + (e&7);
}
__device__ __forceinline__ int swz512(int d, int e){
    return ((d>>4)*16 + (e>>5))*512 + (((e>>3)&3)*16 + (d&15))*8 + (e&7);
}

// ---------------- single merged prepass ----------------
// ws layout (bf16): [0,65536) sMt; [65536,131072) sWg; [131072,262144) sWo; [262144,..) bf16 table
extern "C" __global__ __launch_bounds__(256)
void prep_all(const float* __restrict__ Wq, const float* __restrict__ Wk,
              const float* __restrict__ Wg, const float* __restrict__ Wo,
              const float* __restrict__ embs, unsigned short* __restrict__ ws, int n8)
{
    int bid = blockIdx.x, e = threadIdx.x;
    if (bid < 256) {                      // Mt[d][e] = sum_a Wq[a][e]*Wk[a][d]
        int d = bid; float acc = 0.f;
        #pragma unroll 8
        for (int a = 0; a < 64; ++a) acc = fmaf(Wq[a*256 + e], Wk[a*256 + d], acc);
        ws[swz256(d, e)] = f2b(acc);
    } else if (bid < 512) {
        int r = bid - 256;
        ws[65536 + swz256(r, e)] = f2b(Wg[r*256 + e]);
    } else if (bid < 768) {
        int r = bid - 512;
        ws[131072 + swz512(r, e)]       = f2b(Wo[r*512 + e]);
        ws[131072 + swz512(r, e + 256)] = f2b(Wo[r*512 + 256 + e]);
    } else {                              // table f32 -> bf16 (row-major unchanged)
        int i = (bid - 768)*256 + e;
        if (i < n8) {
            const float4* s = (const float4*)embs + (size_t)i*2;
            float4 a = s[0], b = s[1];
            uint4 o;
            o.x = pack2(a.x,a.y); o.y = pack2(a.z,a.w);
            o.z = pack2(b.x,b.y); o.w = pack2(b.z,b.w);
            ((uint4*)(ws + 262144))[i] = o;
        }
    }
}

// Gather with coalesced lane groups: lane (k = lane>>2, p = lane&3) owns column
// chunks {i*32 + p*8}. For each i, the 4 lanes of a row read contiguous 64B.
template<bool TBF>
__device__ __forceinline__ void gather8(uint4* buf, const unsigned short* tbl,
                                        const float* embs, int idx, int p)
{
    if (TBF) {
        const unsigned short* base = tbl + (size_t)idx*DD + p*8;
        #pragma unroll
        for (int i = 0; i < 8; ++i) buf[i] = *(const uint4*)(base + i*32);
    } else {
        const float* base = embs + (size_t)idx*DD + p*8;
        #pragma unroll
        for (int i = 0; i < 8; ++i) {
            float4 a = *(const float4*)(base + i*32);
            float4 b = *(const float4*)(base + i*32 + 4);
            buf[i].x = pack2(a.x,a.y); buf[i].y = pack2(a.z,a.w);
            buf[i].z = pack2(b.x,b.y); buf[i].w = pack2(b.z,b.w);
        }
    }
}

// ---------------- main fused kernel ----------------
template<bool TBF>
__global__ __launch_bounds__(256, 2)
void na_mfma3(const float* __restrict__ embs,
              const int* __restrict__ cidx,
              const int* __restrict__ nidx,
              const float* __restrict__ nbw,
              const unsigned short* __restrict__ tbl,
              const unsigned short* __restrict__ wMt,
              const unsigned short* __restrict__ wWg,
              const unsigned short* __restrict__ wWo,
              const float* __restrict__ bg,
              const float* __restrict__ bo,
              const float* __restrict__ gamma,
              const float* __restrict__ beta,
              float* __restrict__ out)
{
    __shared__ __align__(16) unsigned short s_ac[16][264];    // center bf16 (A-frags)
    __shared__ __align__(16) unsigned short s_ax[16][264];    // gate bf16 -> gated ctx bf16
    __shared__ __align__(16) float s_t[16][260];              // t f32 -> x f32
    __shared__ __align__(16) unsigned short s_nb[4][16][264]; // per-wave neighbor staging
    __shared__ float s_attn[4][16];
    __shared__ int   s_cidx[16];

    const int tid  = threadIdx.x;
    const int row0 = blockIdx.x * MM;
    const int lane = tid & 63, wv = tid >> 6;
    const int l15  = lane & 15, quad = lane >> 4;
    const ffrag fz = {0.f, 0.f, 0.f, 0.f};

    // ---- P1: stage 16 center rows (f32 -> bf16), coalesced ----
    if (tid < 16) s_cidx[tid] = cidx[row0 + tid];
    {
        int m = tid >> 4, cs = tid & 15;
        int idx = cidx[row0 + m];
        const float4* src = (const float4*)(embs + (size_t)idx * DD + cs * 16);
        float4 a = src[0], b = src[1], c2 = src[2], d2 = src[3];
        uint4 o0, o1;
        o0.x = pack2(a.x,a.y);   o0.y = pack2(a.z,a.w);
        o0.z = pack2(b.x,b.y);   o0.w = pack2(b.z,b.w);
        o1.x = pack2(c2.x,c2.y); o1.y = pack2(c2.z,c2.w);
        o1.z = pack2(d2.x,d2.y); o1.w = pack2(d2.z,d2.w);
        uint4* dst = (uint4*)&s_ac[m][cs * 16];
        dst[0] = o0; dst[1] = o1;
    }
    __syncthreads();

    // ---- P2: t = center.Mt^T (f32 -> s_t) AND gate = sigmoid(center.Wg^T+bg) (bf16 -> s_ax) ----
    {
        ffrag at[4] = {fz,fz,fz,fz}, ag[4] = {fz,fz,fz,fz};
        const unsigned short* ar  = &s_ac[l15][quad * 8];
        const unsigned short* btA = wMt + (size_t)(wv*4)*4096 + lane*8;   // coalesced frags
        const unsigned short* bgA = wWg + (size_t)(wv*4)*4096 + lane*8;
        #pragma unroll
        for (int kc = 0; kc < 8; ++kc) {
            bfrag af = *(const bfrag*)(ar + kc*32);
            #pragma unroll
            for (int t = 0; t < 4; ++t) {
                at[t] = __builtin_amdgcn_mfma_f32_16x16x32_bf16(af, *(const bfrag*)(btA + t*4096 + kc*512), at[t], 0,0,0);
                ag[t] = __builtin_amdgcn_mfma_f32_16x16x32_bf16(af, *(const bfrag*)(bgA + t*4096 + kc*512), ag[t], 0,0,0);
            }
        }
        #pragma unroll
        for (int t = 0; t < 4; ++t) {
            int col = wv*64 + t*16 + l15;
            float bgv = bg[col];
            #pragma unroll
            for (int r = 0; r < 4; ++r) {
                int rr = quad*4 + r;
                s_t[rr][col] = at[t][r];
                float g = 1.f / (1.f + expf(-(ag[t][r] + bgv)));
                s_ax[rr][col] = f2b(g);
            }
        }
    }
    __syncthreads();

    // ---- P3: attention, per-wave, barrier-free, prefetched ----
    {
        const int k = lane >> 2;   // neighbor 0..15
        const int p = lane & 3;    // column sub-chunk within each 32-col group
        int idxs[4];
        #pragma unroll
        for (int j = 0; j < 4; ++j)
            idxs[j] = nidx[(size_t)(row0 + 4*wv + j) * 16 + k];

        uint4 buf[2][8];
        gather8<TBF>(buf[0], tbl, embs, idxs[0], p);

        #pragma unroll
        for (int j = 0; j < 4; ++j) {
            if (j < 3) gather8<TBF>(buf[(j+1)&1], tbl, embs, idxs[j+1], p);
            const int m = 4*wv + j;
            // stage row j's neighbors for the ctx pass (lane's chunks at i*32+p*8)
            unsigned short* nbp = &s_nb[wv][k][p*8];
            #pragma unroll
            for (int i = 0; i < 8; ++i) *(uint4*)(nbp + i*32) = buf[j&1][i];
            // logits partial straight from the prefetch registers
            const float* trow = &s_t[m][p*8];
            float part = 0.f;
            #pragma unroll
            for (int i = 0; i < 8; ++i) {
                uint4 v = buf[j&1][i];
                float4 t0 = *(const float4*)(trow + i*32);
                float4 t1 = *(const float4*)(trow + i*32 + 4);
                part += lo2f(v.x)*t0.x + hi2f(v.x)*t0.y + lo2f(v.y)*t0.z + hi2f(v.y)*t0.w
                      + lo2f(v.z)*t1.x + hi2f(v.z)*t1.y + lo2f(v.w)*t1.z + hi2f(v.w)*t1.w;
            }
            part += __shfl_xor(part, 1);
            part += __shfl_xor(part, 2);
            float wgt = nbw[(size_t)(row0 + m) * 16 + k];
            float lg = part * 0.125f + logf(fmaxf(wgt, 1e-6f));
            float mx = lg;
            mx = fmaxf(mx, __shfl_xor(mx, 4));  mx = fmaxf(mx, __shfl_xor(mx, 8));
            mx = fmaxf(mx, __shfl_xor(mx, 16)); mx = fmaxf(mx, __shfl_xor(mx, 32));
            float e = expf(lg - mx);
            float s = e;
            s += __shfl_xor(s, 4);  s += __shfl_xor(s, 8);
            s += __shfl_xor(s, 16); s += __shfl_xor(s, 32);
            float attn = e / s;
            if (p == 0) s_attn[wv][k] = attn;
            // ctx: lane owns flat cols [4*lane, 4*lane+4); gate applied inline
            float4 aw0 = *(const float4*)&s_attn[wv][0];
            float4 aw1 = *(const float4*)&s_attn[wv][4];
            float4 aw2 = *(const float4*)&s_attn[wv][8];
            float4 aw3 = *(const float4*)&s_attn[wv][12];
            float aarr[16] = {aw0.x,aw0.y,aw0.z,aw0.w, aw1.x,aw1.y,aw1.z,aw1.w,
                              aw2.x,aw2.y,aw2.z,aw2.w, aw3.x,aw3.y,aw3.z,aw3.w};
            float c0=0.f, c1=0.f, c2=0.f, c3=0.f;
            #pragma unroll
            for (int kk = 0; kk < 16; ++kk) {
                uint2 v = *(const uint2*)&s_nb[wv][kk][lane*4];
                float a = aarr[kk];
                c0 += a * lo2f(v.x); c1 += a * hi2f(v.x);
                c2 += a * lo2f(v.y); c3 += a * hi2f(v.y);
            }
            uint2 g = *(const uint2*)&s_ax[m][lane*4];
            c0 *= lo2f(g.x); c1 *= hi2f(g.x); c2 *= lo2f(g.y); c3 *= hi2f(g.y);
            uint2 o; o.x = pack2(c0, c1); o.y = pack2(c2, c3);
            *(uint2*)&s_ax[m][lane*4] = o;
        }
    }
    __syncthreads();

    // ---- P5: x = [center|gated ctx].Wo^T + bo + center_f32 -> s_t ----
    {
        ffrag acc[4] = {fz,fz,fz,fz};
        const unsigned short* arc = &s_ac[l15][quad * 8];
        const unsigned short* arx = &s_ax[l15][quad * 8];
        const unsigned short* bO  = wWo + (size_t)(wv*4)*8192 + lane*8;   // coalesced frags
        #pragma unroll
        for (int kc = 0; kc < 8; ++kc) {          // center half (k 0..255)
            bfrag af = *(const bfrag*)(arc + kc*32);
            #pragma unroll
            for (int t = 0; t < 4; ++t)
                acc[t] = __builtin_amdgcn_mfma_f32_16x16x32_bf16(af, *(const bfrag*)(bO + t*8192 + kc*512), acc[t], 0,0,0);
        }
        #pragma unroll
        for (int kc = 8; kc < 16; ++kc) {         // ctx half (k 256..511)
            bfrag af = *(const bfrag*)(arx + (kc-8)*32);
            #pragma unroll
            for (int t = 0; t < 4; ++t)
                acc[t] = __builtin_amdgcn_mfma_f32_16x16x32_bf16(af, *(const bfrag*)(bO + t*8192 + kc*512), acc[t], 0,0,0);
        }
        #pragma unroll
        for (int t = 0; t < 4; ++t) {
            int col = wv*64 + t*16 + l15;
            float bov = bo[col];
            #pragma unroll
            for (int r = 0; r < 4; ++r) {
                int rr = quad*4 + r;
                float ctr = embs[(size_t)s_cidx[rr] * DD + col];  // f32 residual
                s_t[rr][col] = acc[t][r] + bov + ctr;             // t dead; overwrite with x
            }
        }
    }
    __syncthreads();

    // ---- P6: LayerNorm ----
    {
        #pragma unroll
        for (int jj = 0; jj < 4; ++jj) {
            int m = wv * 4 + jj;
            float x0 = s_t[m][lane],       x1 = s_t[m][64 + lane];
            float x2 = s_t[m][128 + lane], x3 = s_t[m][192 + lane];
            float s  = x0 + x1 + x2 + x3;
            float ss = x0*x0 + x1*x1 + x2*x2 + x3*x3;
            #pragma unroll
            for (int off = 32; off >= 1; off >>= 1) {
                s  += __shfl_xor(s, off);
                ss += __shfl_xor(ss, off);
            }
            float mu  = s * (1.f/256.f);
            float var = ss * (1.f/256.f) - mu*mu;
            float rs  = rsqrtf(var + 1e-5f);
            size_t base = (size_t)(row0 + m) * DD;
            float xs[4] = {x0, x1, x2, x3};
            #pragma unroll
            for (int cc = 0; cc < 4; ++cc) {
                int dd = cc*64 + lane;
                out[base + dd] = (xs[cc] - mu) * rs * gamma[dd] + beta[dd];
            }
        }
    }
}

// ---------------- f32 fallback (only if ws too small) ----------------
#define SD 260
#define KT 16
#define WS 17
extern "C" __global__ __launch_bounds__(256)
void na_f32_kernel(const float* __restrict__ embs, const int* __restrict__ center_idx,
                   const int* __restrict__ nb_idx, const float* __restrict__ nb_w,
                   const float* __restrict__ Wq, const float* __restrict__ Wk,
                   const float* __restrict__ Wg, const float* __restrict__ bg,
                   const float* __restrict__ Wo, const float* __restrict__ bo,
                   const float* __restrict__ gamma, const float* __restrict__ beta,
                   float* __restrict__ out)
{
    __shared__ __align__(16) float s_center[MM][SD];
    __shared__ __align__(16) float s_tc[MM][SD];
    __shared__ __align__(16) float s_nb[16][SD];
    __shared__ __align__(16) float s_w[DD][WS];
    __shared__ __align__(16) float s_q[MM][64];
    __shared__ float s_red[16][16];
    __shared__ float s_attn[16];
    const int tid = threadIdx.x;
    const int row0 = blockIdx.x * MM;
    const int td = tid & 63, tm = tid >> 6;
    {
        int m = tid >> 4, c = tid & 15;
        int idx = center_idx[row0 + m];
        const float4* src = (const float4*)(embs + (size_t)idx * DD) + c * 4;
        float4* dst = (float4*)&s_center[m][c * 16];
        dst[0]=src[0]; dst[1]=src[1]; dst[2]=src[2]; dst[3]=src[3];
    }
    __syncthreads();
    {
        const int a = tid & 63, mg = tid >> 6;
        float qacc[4] = {0,0,0,0};
        for (int kt = 0; kt < DD; kt += KT) {
            __syncthreads();
            { int r = tid >> 2, c4 = (tid & 3) * 4;
              *(float4*)&s_w[r][c4] = *(const float4*)(Wq + r * DD + kt + c4); }
            __syncthreads();
            #pragma unroll
            for (int kk = 0; kk < KT; kk += 4) {
                float4 b = *(const float4*)&s_w[a][kk];
                #pragma unroll
                for (int i = 0; i < 4; ++i) {
                    float4 av = *(const float4*)&s_center[4*mg + i][kt + kk];
                    qacc[i] += av.x*b.x + av.y*b.y + av.z*b.z + av.w*b.w;
                }
            }
        }
        __syncthreads();
        #pragma unroll
        for (int i = 0; i < 4; ++i) s_q[4*mg + i][a] = qacc[i];
    }
    __syncthreads();
    {
        float tacc[4][4];
        #pragma unroll
        for (int i=0;i<4;++i) { tacc[i][0]=tacc[i][1]=tacc[i][2]=tacc[i][3]=0.f; }
        for (int kk = 0; kk < 64; kk += 4) {
            float4 bk[4];
            #pragma unroll
            for (int t4 = 0; t4 < 4; ++t4)
                bk[t4] = *(const float4*)(Wk + (size_t)(kk + t4) * DD + 4 * td);
            #pragma unroll
            for (int i = 0; i < 4; ++i) {
                float4 av = *(const float4*)&s_q[4*tm + i][kk];
                tacc[i][0] += av.x*bk[0].x + av.y*bk[1].x + av.z*bk[2].x + av.w*bk[3].x;
                tacc[i][1] += av.x*bk[0].y + av.y*bk[1].y + av.z*bk[2].y + av.w*bk[3].y;
                tacc[i][2] += av.x*bk[0].z + av.y*bk[1].z + av.z*bk[2].z + av.w*bk[3].z;
                tacc[i][3] += av.x*bk[0].w + av.y*bk[1].w + av.z*bk[2].w + av.w*bk[3].w;
            }
        }
        #pragma unroll
        for (int i = 0; i < 4; ++i)
            *(float4*)&s_tc[4*tm + i][4*td] = make_float4(tacc[i][0],tacc[i][1],tacc[i][2],tacc[i][3]);
    }
    __syncthreads();
    for (int m = 0; m < MM; ++m) {
        { int k = tid >> 4, c = tid & 15;
          int idx = nb_idx[(row0 + m) * 16 + k];
          const float4* src = (const float4*)(embs + (size_t)idx * DD) + c * 4;
          float4* dst = (float4*)&s_nb[k][c * 16];
          dst[0]=src[0]; dst[1]=src[1]; dst[2]=src[2]; dst[3]=src[3]; }
        __syncthreads();
        { int k = tid >> 4, i = tid & 15;
          float acc = 0.f;
          #pragma unroll
          for (int j4 = 0; j4 < 4; ++j4) {
              float4 nv = *(const float4*)&s_nb[k][i*16 + 4*j4];
              float4 tv = *(const float4*)&s_tc[m][i*16 + 4*j4];
              acc += nv.x*tv.x + nv.y*tv.y + nv.z*tv.z + nv.w*tv.w;
          }
          s_red[k][i] = acc; }
        __syncthreads();
        if (tid < 16) {
            float lg = 0.f;
            #pragma unroll
            for (int i = 0; i < 16; ++i) lg += s_red[tid][i];
            float wv2 = nb_w[(row0 + m) * 16 + tid];
            lg = lg * 0.125f + logf(fmaxf(wv2, 1e-6f));
            float mx = lg;
            #pragma unroll
            for (int off = 8; off >= 1; off >>= 1) mx = fmaxf(mx, __shfl_xor(mx, off));
            float e = expf(lg - mx);
            float s = e;
            #pragma unroll
            for (int off = 8; off >= 1; off >>= 1) s += __shfl_xor(s, off);
            s_attn[tid] = e / s;
        }
        __syncthreads();
        { float acc = 0.f;
          #pragma unroll
          for (int k = 0; k < 16; ++k) acc += s_attn[k] * s_nb[k][tid];
          s_tc[m][tid] = acc; }
        __syncthreads();
    }
    {
        float acc[4][4];
        #pragma unroll
        for (int i=0;i<4;++i){acc[i][0]=acc[i][1]=acc[i][2]=acc[i][3]=0.f;}
        for (int kt = 0; kt < DD; kt += KT) {
            __syncthreads();
            #pragma unroll
            for (int j = 0; j < 4; ++j) {
                int r = (tid >> 2) + 64 * j, c4 = (tid & 3) * 4;
                *(float4*)&s_w[r][c4] = *(const float4*)(Wg + (size_t)r * DD + kt + c4);
            }
            __syncthreads();
            #pragma unroll
            for (int kk = 0; kk < KT; kk += 4) {
                float4 b[4];
                #pragma unroll
                for (int j = 0; j < 4; ++j) b[j] = *(const float4*)&s_w[4*td + j][kk];
                #pragma unroll
                for (int i = 0; i < 4; ++i) {
                    float4 av = *(const float4*)&s_center[4*tm + i][kt + kk];
                    #pragma unroll
                    for (int j = 0; j < 4; ++j)
                        acc[i][j] += av.x*b[j].x + av.y*b[j].y + av.z*b[j].z + av.w*b[j].w;
                }
            }
        }
        float bgv[4];
        #pragma unroll
        for (int j = 0; j < 4; ++j) bgv[j] = bg[4*td + j];
        __syncthreads();
        #pragma unroll
        for (int i = 0; i < 4; ++i)
            #pragma unroll
            for (int j = 0; j < 4; ++j) {
                float g = 1.f / (1.f + expf(-(acc[i][j] + bgv[j])));
                s_tc[4*tm + i][4*td + j] *= g;
            }
    }
    {
        float acc[4][4];
        #pragma unroll
        for (int i=0;i<4;++i){acc[i][0]=acc[i][1]=acc[i][2]=acc[i][3]=0.f;}
        for (int kt = 0; kt < 2*DD; kt += KT) {
            __syncthreads();
            #pragma unroll
            for (int j = 0; j < 4; ++j) {
                int r = (tid >> 2) + 64 * j, c4 = (tid & 3) * 4;
                *(float4*)&s_w[r][c4] = *(const float4*)(Wo + (size_t)r * 2 * DD + kt + c4);
            }
            __syncthreads();
            const float* Abase = (kt < DD) ? &s_center[0][0] : &s_tc[0][0];
            const int kb = (kt < DD) ? kt : kt - DD;
            #pragma unroll
            for (int kk = 0; kk < KT; kk += 4) {
                float4 b[4];
                #pragma unroll
                for (int j = 0; j < 4; ++j) b[j] = *(const float4*)&s_w[4*td + j][kk];
                #pragma unroll
                for (int i = 0; i < 4; ++i) {
                    float4 av = *(const float4*)(Abase + (4*tm + i) * SD + kb + kk);
                    #pragma unroll
                    for (int j = 0; j < 4; ++j)
                        acc[i][j] += av.x*b[j].x + av.y*b[j].y + av.z*b[j].z + av.w*b[j].w;
                }
            }
        }
        float bov[4];
        #pragma unroll
        for (int j = 0; j < 4; ++j) bov[j] = bo[4*td + j];
        __syncthreads();
        #pragma unroll
        for (int i = 0; i < 4; ++i)
            #pragma unroll
            for (int j = 0; j < 4; ++j)
                s_tc[4*tm + i][4*td + j] = acc[i][j] + bov[j] + s_center[4*tm + i][4*td + j];
    }
    __syncthreads();
    {
        int wv2 = tid >> 6, lane = tid & 63;
        #pragma unroll
        for (int jj = 0; jj < 4; ++jj) {
            int m = wv2 * 4 + jj;
            float x0 = s_tc[m][lane],       x1 = s_tc[m][64 + lane];
            float x2 = s_tc[m][128 + lane], x3 = s_tc[m][192 + lane];
            float s  = x0+x1+x2+x3;
            float ss = x0*x0 + x1*x1 + x2*x2 + x3*x3;
            #pragma unroll
            for (int off = 32; off >= 1; off >>= 1) { s += __shfl_xor(s, off); ss += __shfl_xor(ss, off); }
            float mu = s * (1.f/256.f);
            float var = ss * (1.f/256.f) - mu*mu;
            float rs = rsqrtf(var + 1e-5f);
            size_t base = (size_t)(row0 + m) * DD;
            float xs[4] = {x0,x1,x2,x3};
            #pragma unroll
            for (int c = 0; c < 4; ++c) {
                int dd = c*64 + lane;
                out[base + dd] = (xs[c] - mu) * rs * gamma[dd] + beta[dd];
            }
        }
    }
}

extern "C" void kernel_launch(void* const* d_in, const int* in_sizes, int n_in,
                              void* d_out, int out_size, void* d_ws, size_t ws_size,
                              hipStream_t stream) {
    const float* embs  = (const float*)d_in[0];
    const int*   cidx  = (const int*)d_in[1];
    const int*   nidx  = (const int*)d_in[2];
    const float* nbw   = (const float*)d_in[3];
    const float* Wq    = (const float*)d_in[4];
    const float* Wk    = (const float*)d_in[5];
    const float* Wg    = (const float*)d_in[6];
    const float* bg    = (const float*)d_in[7];
    const float* Wo    = (const float*)d_in[8];
    const float* bo    = (const float*)d_in[9];
    const float* gamma = (const float*)d_in[10];
    const float* beta  = (const float*)d_in[11];
    float* out = (float*)d_out;

    const int B = in_sizes[1];
    const int nemb = in_sizes[0];
    const size_t need_w = 262144 * 2;
    const size_t need_t = need_w + (size_t)nemb * 2;

    if (ws_size < need_w) {
        hipLaunchKernelGGL(na_f32_kernel, dim3(B / MM), dim3(256), 0, stream,
                           embs, cidx, nidx, nbw, Wq, Wk, Wg, bg, Wo, bo, gamma, beta, out);
        return;
    }
    unsigned short* wsb = (unsigned short*)d_ws;
    const bool use_tbl = (ws_size >= need_t) && ((nemb & 7) == 0);
    const int n8 = use_tbl ? (nemb / 8) : 0;
    const int prep_grid = 768 + (use_tbl ? (n8 + 255) / 256 : 0);
    hipLaunchKernelGGL(prep_all, dim3(prep_grid), dim3(256), 0, stream,
                       Wq, Wk, Wg, Wo, embs, wsb, n8);

    if (use_tbl) {
        hipLaunchKernelGGL(na_mfma3<true>, dim3(B / MM), dim3(256), 0, stream,
                           embs, cidx, nidx, nbw, wsb + 262144,
                           wsb, wsb + 65536, wsb + 131072,
                           bg, bo, gamma, beta, out);
    } else {
        hipLaunchKernelGGL(na_mfma3<false>, dim3(B / MM), dim3(256), 0, stream,
                           embs, cidx, nidx, nbw, (const unsigned short*)nullptr,
                           wsb, wsb + 65536, wsb + 131072,
                           bg, bo, gamma, beta, out);
    }
}